// Round 7
// baseline (161.138 us; speedup 1.0000x reference)
//
#include <hip/hip_runtime.h>
#include <stdint.h>

#define LOG2E 1.44269504088896340736f
#define QSCALE (0.125f * LOG2E)   // dim_head^-0.5 folded with log2(e) for exp2-domain softmax

typedef __bf16 bf16x8 __attribute__((ext_vector_type(8)));
typedef float floatx4 __attribute__((ext_vector_type(4)));
typedef unsigned short ushort8v __attribute__((ext_vector_type(8)));

__device__ __forceinline__ unsigned short bfbits(float f) {
  __bf16 h = (__bf16)f;
  return __builtin_bit_cast(unsigned short, h);
}

__device__ __forceinline__ float fast_exp2(float x) {
#if __has_builtin(__builtin_amdgcn_exp2f)
  return __builtin_amdgcn_exp2f(x);
#else
  return exp2f(x);
#endif
}

__device__ __forceinline__ void gl2lds16(const void* g, void* l) {
  __builtin_amdgcn_global_load_lds((const __attribute__((address_space(1))) void*)g,
                                   (__attribute__((address_space(3))) void*)l, 16, 0, 0);
}

// ---------------- prep: transpose-cvt of Wq/Wkv/Wo only (in[512][N] -> out[N][512] bf16) ----------------
__global__ __launch_bounds__(256)
void prep_kernel(const float* __restrict__ Wq, const float* __restrict__ Wkv,
                 const float* __restrict__ Wo,
                 unsigned short* __restrict__ WqT, unsigned short* __restrict__ WkvT,
                 unsigned short* __restrict__ WoT) {
  __shared__ float tile[32][33];
  int t = blockIdx.x;  // 0..1023
  int tid = threadIdx.x;
  const float* in; unsigned short* out; int N; int tb;
  if (t < 256)      { in = Wq;  out = WqT;  N = 512;  tb = t; }
  else if (t < 768) { in = Wkv; out = WkvT; N = 1024; tb = t - 256; }
  else              { in = Wo;  out = WoT;  N = 512;  tb = t - 768; }
  const int K = 512;
  int nbx = N / 32;
  int n0 = (tb % nbx) * 32, k0 = (tb / nbx) * 32;
  int tx = tid & 31, ty = tid >> 5;
#pragma unroll
  for (int r = ty; r < 32; r += 8)
    tile[r][tx] = in[(long)(k0 + r) * N + n0 + tx];
  __syncthreads();
#pragma unroll
  for (int r = ty; r < 32; r += 8)
    out[(long)(n0 + r) * K + k0 + tx] = bfbits(tile[tx][r]);
}

// ---------------- proj: fused Q-proj and KV-proj GEMMs, 128x128x32 tiles ----------------
// A is fp32 (x or ctx), converted to bf16 in-register during LDS staging.
// blocks 0..255: Q = x*Wq -> Qb[b,h,n,d] (scaled). 256..767: KV = ctx*Wkv
//   -> Kb[b,h,m,d] (bn<512) / Vt[b,h,d,m] (bn>=512, 8B packed).
__global__ __launch_bounds__(256)
void proj_gemm(const float* __restrict__ Xf, const float* __restrict__ Cf,
               const unsigned short* __restrict__ WqT, const unsigned short* __restrict__ WkvT,
               unsigned short* __restrict__ Qb, unsigned short* __restrict__ Kb,
               unsigned short* __restrict__ Vt) {
  __shared__ unsigned short As[128 * 32];
  __shared__ unsigned short Bs[128 * 32];

  int idx = blockIdx.x;
  const float* A; const unsigned short* Bt;
  long bm, bn; int role;
  if (idx < 256) { role = 0; A = Xf; Bt = WqT;  bn = (long)(idx & 3) * 128; bm = (long)(idx >> 2) * 128; }
  else { idx -= 256; role = 1; A = Cf; Bt = WkvT; bn = (long)(idx & 7) * 128; bm = (long)(idx >> 3) * 128; }

  const int tid = threadIdx.x;
  const int wave = tid >> 6;
  const int lane = tid & 63;
  const int l15 = lane & 15;
  const int q4 = lane >> 4;
  const int wm = (wave & 1) * 64;
  const int wn = (wave >> 1) * 64;
  const int K = 512;

  floatx4 acc[4][4];
#pragma unroll
  for (int i = 0; i < 4; ++i)
#pragma unroll
    for (int j = 0; j < 4; ++j) { acc[i][j][0]=0.f; acc[i][j][1]=0.f; acc[i][j][2]=0.f; acc[i][j][3]=0.f; }

  for (int k0 = 0; k0 < K; k0 += 32) {
    // B: bf16, async direct-to-LDS
#pragma unroll
    for (int cc = 0; cc < 2; ++cc) {
      int c = cc * 256 + tid;
      int r = c >> 2, kc = c & 3;
      gl2lds16(Bt + (bn + r) * (long)K + k0 + kc * 8, (char*)Bs + c * 16);
    }
    // A: fp32 -> bf16 in-register, ds_write_b128 to same layout (conflict-free, consecutive 16B/lane)
#pragma unroll
    for (int cc = 0; cc < 2; ++cc) {
      int c = cc * 256 + tid;
      int r = c >> 2, kc = c & 3;
      const float* src = A + (bm + r) * (long)K + k0 + kc * 8;
      float4 u0 = *(const float4*)src;
      float4 u1 = *(const float4*)(src + 4);
      ushort8v pk;
      pk[0] = bfbits(u0.x); pk[1] = bfbits(u0.y); pk[2] = bfbits(u0.z); pk[3] = bfbits(u0.w);
      pk[4] = bfbits(u1.x); pk[5] = bfbits(u1.y); pk[6] = bfbits(u1.z); pk[7] = bfbits(u1.w);
      *(ushort8v*)(As + c * 8) = pk;
    }
    __syncthreads();
    bf16x8 af[4], bfr[4];
#pragma unroll
    for (int i = 0; i < 4; ++i)
      af[i] = *(const bf16x8*)(As + (wm + i * 16 + l15) * 32 + q4 * 8);
#pragma unroll
    for (int j = 0; j < 4; ++j)
      bfr[j] = *(const bf16x8*)(Bs + (wn + j * 16 + l15) * 32 + q4 * 8);
#pragma unroll
    for (int i = 0; i < 4; ++i)
#pragma unroll
      for (int j = 0; j < 4; ++j)
        acc[i][j] = __builtin_amdgcn_mfma_f32_16x16x32_bf16(af[i], bfr[j], acc[i][j], 0, 0, 0);
    __syncthreads();
  }

  const bool vrole = (role == 1) && (bn >= 512);
#pragma unroll
  for (int i = 0; i < 4; ++i) {
#pragma unroll
    for (int j = 0; j < 4; ++j) {
      long col = bn + wn + j * 16 + l15;
      if (vrole) {
        long h = (col - 512) >> 6, d = col & 63;
        long row0 = bm + wm + i * 16 + q4 * 4;
        long b = row0 >> 10, m0 = row0 & 1023;
        unsigned long long pk = (unsigned long long)bfbits(acc[i][j][0])
                              | ((unsigned long long)bfbits(acc[i][j][1]) << 16)
                              | ((unsigned long long)bfbits(acc[i][j][2]) << 32)
                              | ((unsigned long long)bfbits(acc[i][j][3]) << 48);
        *(unsigned long long*)(Vt + ((b * 8 + h) * 64 + d) * 1024 + m0) = pk;
      } else {
        long h = col >> 6, d = col & 63;
#pragma unroll
        for (int r = 0; r < 4; ++r) {
          long row = bm + wm + i * 16 + q4 * 4 + r;
          long b = row >> 10, n = row & 1023;
          float v = acc[i][j][r];
          if (role == 0) Qb[((b * 8 + h) * 1024 + n) * 64 + d] = bfbits(v * QSCALE);
          else           Kb[((b * 8 + h) * 1024 + n) * 64 + d] = bfbits(v);
        }
      }
    }
  }
}

// ---------------- flash attention: 128 q/block, 32 q/wave, S^T softmax (R5 config) ----------------
// grid (64 bh, 8 nb), 256 threads. KV tiles of 64, double-buffered. LDS 48KB.
__global__ __launch_bounds__(256)
void attn_kernel(const unsigned short* __restrict__ Qb,  // [64][1024][64] (pre-scaled)
                 const unsigned short* __restrict__ Kb,  // [64][1024][64]
                 const unsigned short* __restrict__ Vt,  // [64][64][1024]
                 unsigned short* __restrict__ Ob)        // [8192][512]
{
  __shared__ unsigned short Ksm[2][4096];  // [64 kv][64 d], 16B-chunk XOR swizzle
  __shared__ unsigned short Vsm[2][4096];  // [64 d][64 m], 16B-chunk XOR swizzle
  __shared__ unsigned short Psm[128 * 64]; // [128 q][64 kv], wave-private 32-row bands

  const int tid = threadIdx.x;
  const int wave = tid >> 6;
  const int lane = tid & 63;
  const int l15 = lane & 15;
  const int q4 = lane >> 4;
  const int bh = blockIdx.x;
  const int nb = blockIdx.y;

  const long qrow0 = (long)bh * 1024 + nb * 128 + wave * 32;

  // Q B-frags: B[n=l15 (qrow)][k=q4*8+j (d)], two 16-row groups
  bf16x8 qf[2][2];
#pragma unroll
  for (int qn = 0; qn < 2; ++qn)
#pragma unroll
    for (int ks = 0; ks < 2; ++ks)
      qf[qn][ks] = *(const bf16x8*)(Qb + (qrow0 + qn * 16 + l15) * 64 + ks * 32 + q4 * 8);

  floatx4 acc[2][4];
#pragma unroll
  for (int i = 0; i < 2; ++i)
#pragma unroll
    for (int d = 0; d < 4; ++d) { acc[i][d][0]=0.f; acc[i][d][1]=0.f; acc[i][d][2]=0.f; acc[i][d][3]=0.f; }
  float suml[2] = {0.0f, 0.0f};

  const unsigned short* Kbase = Kb + (long)bh * 65536;
  const unsigned short* Vbase = Vt + (long)bh * 65536;
  int koff[2], voff[2], lds16[2];
#pragma unroll
  for (int cc = 0; cc < 2; ++cc) {
    int c = cc * 256 + tid;
    int jrow = c >> 3;
    int cact = (c & 7) ^ (jrow & 7);
    koff[cc] = jrow * 64 + cact * 8;
    voff[cc] = jrow * 1024 + cact * 8;
    lds16[cc] = c * 16;
  }
#pragma unroll
  for (int cc = 0; cc < 2; ++cc) {
    gl2lds16(Kbase + koff[cc], (char*)Ksm[0] + lds16[cc]);
    gl2lds16(Vbase + voff[cc], (char*)Vsm[0] + lds16[cc]);
  }

  for (int t = 0; t < 16; ++t) {
    __syncthreads();
    const int cur = t & 1;
    if (t + 1 < 16) {
      const int nxt = cur ^ 1;
#pragma unroll
      for (int cc = 0; cc < 2; ++cc) {
        gl2lds16(Kbase + (t + 1) * 4096 + koff[cc], (char*)Ksm[nxt] + lds16[cc]);
        gl2lds16(Vbase + (t + 1) * 64 + voff[cc], (char*)Vsm[nxt] + lds16[cc]);
      }
    }

    // S^T = K Q^T : st[jn][qn]: C col=l15 -> q (qn*16+l15), row=q4*4+r -> kv (jn*16+q4*4+r)
    floatx4 st[4][2];
#pragma unroll
    for (int jn = 0; jn < 4; ++jn)
#pragma unroll
      for (int qn = 0; qn < 2; ++qn) { st[jn][qn][0]=0.f; st[jn][qn][1]=0.f; st[jn][qn][2]=0.f; st[jn][qn][3]=0.f; }
#pragma unroll
    for (int ks = 0; ks < 2; ++ks) {
      bf16x8 kfr[4];
#pragma unroll
      for (int jn = 0; jn < 4; ++jn) {
        int j = jn * 16 + l15;
        int cact = (ks * 4 + q4) ^ (j & 7);
        kfr[jn] = *(const bf16x8*)(Ksm[cur] + j * 64 + cact * 8);
      }
#pragma unroll
      for (int jn = 0; jn < 4; ++jn)
#pragma unroll
        for (int qn = 0; qn < 2; ++qn)
          st[jn][qn] = __builtin_amdgcn_mfma_f32_16x16x32_bf16(kfr[jn], qf[qn][ks], st[jn][qn], 0, 0, 0);
    }

    // p = exp2(s); per-lane partial row sums; packed b64 P writes (4 consecutive kv)
#pragma unroll
    for (int qn = 0; qn < 2; ++qn) {
      int prow = wave * 32 + qn * 16 + l15;
#pragma unroll
      for (int jn = 0; jn < 4; ++jn) {
        float p0 = fast_exp2(st[jn][qn][0]);
        float p1 = fast_exp2(st[jn][qn][1]);
        float p2 = fast_exp2(st[jn][qn][2]);
        float p3 = fast_exp2(st[jn][qn][3]);
        suml[qn] += (p0 + p1) + (p2 + p3);
        unsigned long long pk = (unsigned long long)bfbits(p0)
                              | ((unsigned long long)bfbits(p1) << 16)
                              | ((unsigned long long)bfbits(p2) << 32)
                              | ((unsigned long long)bfbits(p3) << 48);
        int ch16 = (jn * 2 + (q4 >> 1)) ^ (prow & 7);
        *(unsigned long long*)(Psm + prow * 64 + ch16 * 8 + (q4 & 1) * 4) = pk;
      }
    }
    __asm__ volatile("s_waitcnt lgkmcnt(0)" ::: "memory");  // P rows are wave-private

    // O += P V : A-frag from Psm (m=q), B-frag from Vsm (n=d)
#pragma unroll
    for (int ks = 0; ks < 2; ++ks) {
      bf16x8 pa[2], vb[4];
#pragma unroll
      for (int i = 0; i < 2; ++i) {
        int m = wave * 32 + i * 16 + l15;
        int cact = (ks * 4 + q4) ^ (m & 7);
        pa[i] = *(const bf16x8*)(Psm + m * 64 + cact * 8);
      }
#pragma unroll
      for (int dn = 0; dn < 4; ++dn) {
        int dd = dn * 16 + l15;
        int cact = (ks * 4 + q4) ^ (dd & 7);
        vb[dn] = *(const bf16x8*)(Vsm[cur] + dd * 64 + cact * 8);
      }
#pragma unroll
      for (int i = 0; i < 2; ++i)
#pragma unroll
        for (int dn = 0; dn < 4; ++dn)
          acc[i][dn] = __builtin_amdgcn_mfma_f32_16x16x32_bf16(pa[i], vb[dn], acc[i][dn], 0, 0, 0);
    }
  }

  // row sums: lanes l15, l15+16, l15+32, l15+48 hold partials for q=qn*16+l15
  float inv[2], invr[2][4];
#pragma unroll
  for (int qn = 0; qn < 2; ++qn) {
    float l = suml[qn];
    l += __shfl_xor(l, 16, 64);
    l += __shfl_xor(l, 32, 64);
    inv[qn] = 1.0f / l;
#pragma unroll
    for (int r = 0; r < 4; ++r) invr[qn][r] = __shfl(inv[qn], q4 * 4 + r, 64);
  }

  const int b = bh >> 3, h = bh & 7;
#pragma unroll
  for (int i = 0; i < 2; ++i) {
#pragma unroll
    for (int dn = 0; dn < 4; ++dn) {
#pragma unroll
      for (int r = 0; r < 4; ++r) {
        long row = (long)b * 1024 + nb * 128 + wave * 32 + i * 16 + q4 * 4 + r;
        long col = h * 64 + dn * 16 + l15;
        Ob[row * 512 + col] = bfbits(acc[i][dn][r] * invr[i][r]);
      }
    }
  }
}

// ---------------- final GEMM: out = Ob * WoT^T + bias, fp32 out, 64x128x32 ----------------
__global__ __launch_bounds__(256)
void out_gemm(const unsigned short* __restrict__ A,   // Ob [8192][512]
              const unsigned short* __restrict__ Bt,  // WoT [512][512]
              float* __restrict__ outF, const float* __restrict__ bias) {
  __shared__ unsigned short As[64 * 32];
  __shared__ unsigned short Bs[128 * 32];

  const int tid = threadIdx.x;
  const int wave = tid >> 6;
  const int lane = tid & 63;
  const int l15 = lane & 15;
  const int q4 = lane >> 4;
  const int wm = (wave & 1) * 32;
  const int wn = (wave >> 1) * 64;
  const long bm = (long)blockIdx.y * 64;
  const long bn = (long)blockIdx.x * 128;
  const int K = 512, N = 512;

  floatx4 acc[2][4];
#pragma unroll
  for (int i = 0; i < 2; ++i)
#pragma unroll
    for (int j = 0; j < 4; ++j) { acc[i][j][0]=0.f; acc[i][j][1]=0.f; acc[i][j][2]=0.f; acc[i][j][3]=0.f; }

  for (int k0 = 0; k0 < K; k0 += 32) {
    {
      int r = tid >> 2, kc = tid & 3;
      gl2lds16(A + (bm + r) * (long)K + k0 + kc * 8, (char*)As + tid * 16);
    }
#pragma unroll
    for (int cc = 0; cc < 2; ++cc) {
      int c = cc * 256 + tid;
      int r = c >> 2, kc = c & 3;
      gl2lds16(Bt + (bn + r) * (long)K + k0 + kc * 8, (char*)Bs + c * 16);
    }
    __syncthreads();
    bf16x8 af[2], bfr[4];
#pragma unroll
    for (int i = 0; i < 2; ++i)
      af[i] = *(const bf16x8*)(As + (wm + i * 16 + l15) * 32 + q4 * 8);
#pragma unroll
    for (int j = 0; j < 4; ++j)
      bfr[j] = *(const bf16x8*)(Bs + (wn + j * 16 + l15) * 32 + q4 * 8);
#pragma unroll
    for (int i = 0; i < 2; ++i)
#pragma unroll
      for (int j = 0; j < 4; ++j)
        acc[i][j] = __builtin_amdgcn_mfma_f32_16x16x32_bf16(af[i], bfr[j], acc[i][j], 0, 0, 0);
    __syncthreads();
  }

#pragma unroll
  for (int i = 0; i < 2; ++i) {
#pragma unroll
    for (int j = 0; j < 4; ++j) {
      long col = bn + wn + j * 16 + l15;
      float bv = bias[col];
#pragma unroll
      for (int r = 0; r < 4; ++r) {
        long row = bm + wm + i * 16 + q4 * 4 + r;
        outF[row * (long)N + col] = acc[i][j][r] + bv;
      }
    }
  }
}

extern "C" void kernel_launch(void* const* d_in, const int* in_sizes, int n_in,
                              void* d_out, int out_size, void* d_ws, size_t ws_size,
                              hipStream_t stream) {
  const float* x   = (const float*)d_in[0];   // [8,1024,512]
  const float* ctx = (const float*)d_in[1];   // [8,1024,512]
  const float* Wq  = (const float*)d_in[2];   // [512,512]
  const float* Wkv = (const float*)d_in[3];   // [512,1024]
  const float* Wo  = (const float*)d_in[4];   // [512,512]
  const float* bo  = (const float*)d_in[5];   // [512]
  float* out = (float*)d_out;

  char* ws = (char*)d_ws;
  unsigned short* WqT  = (unsigned short*)(ws);                 // 0.5 MB
  unsigned short* WkvT = (unsigned short*)(ws + (1u  << 20));   // 1 MB
  unsigned short* WoT  = (unsigned short*)(ws + (2u  << 20));   // 0.5 MB
  unsigned short* Qb   = (unsigned short*)(ws + (4u  << 20));   // 8 MB
  unsigned short* Kb   = (unsigned short*)(ws + (12u << 20));   // 8 MB
  unsigned short* Vt   = (unsigned short*)(ws + (20u << 20));   // 8 MB
  unsigned short* Ob   = (unsigned short*)(ws + (28u << 20));   // 8 MB  (total 36 MB)

  prep_kernel<<<1024, 256, 0, stream>>>(Wq, Wkv, Wo, WqT, WkvT, WoT);
  proj_gemm<<<768, 256, 0, stream>>>(x, ctx, WqT, WkvT, Qb, Kb, Vt);
  attn_kernel<<<dim3(64, 8), 256, 0, stream>>>(Qb, Kb, Vt, Ob);
  out_gemm<<<dim3(4, 128), 256, 0, stream>>>(Ob, WoT, out, bo);
}

// Round 8
// 153.525 us; speedup vs baseline: 1.0496x; 1.0496x over previous
//
#include <hip/hip_runtime.h>
#include <stdint.h>

#define LOG2E 1.44269504088896340736f
#define QSCALE (0.125f * LOG2E)   // dim_head^-0.5 folded with log2(e) for exp2-domain softmax

typedef __bf16 bf16x8 __attribute__((ext_vector_type(8)));
typedef float floatx4 __attribute__((ext_vector_type(4)));

__device__ __forceinline__ unsigned short bfbits(float f) {
  __bf16 h = (__bf16)f;
  return __builtin_bit_cast(unsigned short, h);
}

__device__ __forceinline__ float fast_exp2(float x) {
#if __has_builtin(__builtin_amdgcn_exp2f)
  return __builtin_amdgcn_exp2f(x);
#else
  return exp2f(x);
#endif
}

__device__ __forceinline__ void gl2lds16(const void* g, void* l) {
  __builtin_amdgcn_global_load_lds((const __attribute__((address_space(1))) void*)g,
                                   (__attribute__((address_space(3))) void*)l, 16, 0, 0);
}

// ---------------- prep: fp32->bf16 cvt of x/ctx + transpose-cvt of Wq/Wkv/Wo ----------------
__global__ __launch_bounds__(256)
void prep_kernel(const float* __restrict__ x, const float* __restrict__ ctx,
                 const float* __restrict__ Wq, const float* __restrict__ Wkv,
                 const float* __restrict__ Wo,
                 unsigned short* __restrict__ Xb, unsigned short* __restrict__ Cb,
                 unsigned short* __restrict__ WqT, unsigned short* __restrict__ WkvT,
                 unsigned short* __restrict__ WoT) {
  int blk = blockIdx.x;
  int tid = threadIdx.x;
  if (blk < 8192) {
    const float* in = blk < 4096 ? x : ctx;
    unsigned short* out = blk < 4096 ? Xb : Cb;
    int i = (((blk & 4095) * 256) + tid) * 4;
    float4 v = *(const float4*)(in + i);
    unsigned long long pk = (unsigned long long)bfbits(v.x)
                          | ((unsigned long long)bfbits(v.y) << 16)
                          | ((unsigned long long)bfbits(v.z) << 32)
                          | ((unsigned long long)bfbits(v.w) << 48);
    *(unsigned long long*)(out + i) = pk;
  } else {
    __shared__ float tile[32][33];
    int t = blk - 8192;  // 0..1023
    const float* in; unsigned short* out; int N; int tb;
    if (t < 256)      { in = Wq;  out = WqT;  N = 512;  tb = t; }
    else if (t < 768) { in = Wkv; out = WkvT; N = 1024; tb = t - 256; }
    else              { in = Wo;  out = WoT;  N = 512;  tb = t - 768; }
    const int K = 512;
    int nbx = N / 32;
    int n0 = (tb % nbx) * 32, k0 = (tb / nbx) * 32;
    int tx = tid & 31, ty = tid >> 5;
#pragma unroll
    for (int r = ty; r < 32; r += 8)
      tile[r][tx] = in[(long)(k0 + r) * N + n0 + tx];
    __syncthreads();
#pragma unroll
    for (int r = ty; r < 32; r += 8)
      out[(long)(n0 + r) * K + k0 + tx] = bfbits(tile[tx][r]);
  }
}

// ---------------- proj: fused Q-proj and KV-proj GEMMs, 128x128x32 tiles ----------------
__global__ __launch_bounds__(256)
void proj_gemm(const unsigned short* __restrict__ Xb, const unsigned short* __restrict__ Cb,
               const unsigned short* __restrict__ WqT, const unsigned short* __restrict__ WkvT,
               unsigned short* __restrict__ Qb, unsigned short* __restrict__ Kb,
               unsigned short* __restrict__ Vt) {
  __shared__ unsigned short As[128 * 32];
  __shared__ unsigned short Bs[128 * 32];

  int idx = blockIdx.x;
  const unsigned short* A; const unsigned short* Bt;
  long bm, bn; int role;
  if (idx < 256) { role = 0; A = Xb; Bt = WqT;  bn = (long)(idx & 3) * 128; bm = (long)(idx >> 2) * 128; }
  else { idx -= 256; role = 1; A = Cb; Bt = WkvT; bn = (long)(idx & 7) * 128; bm = (long)(idx >> 3) * 128; }

  const int tid = threadIdx.x;
  const int wave = tid >> 6;
  const int lane = tid & 63;
  const int l15 = lane & 15;
  const int q4 = lane >> 4;
  const int wm = (wave & 1) * 64;
  const int wn = (wave >> 1) * 64;
  const int K = 512;

  floatx4 acc[4][4];
#pragma unroll
  for (int i = 0; i < 4; ++i)
#pragma unroll
    for (int j = 0; j < 4; ++j) { acc[i][j][0]=0.f; acc[i][j][1]=0.f; acc[i][j][2]=0.f; acc[i][j][3]=0.f; }

  for (int k0 = 0; k0 < K; k0 += 32) {
#pragma unroll
    for (int cc = 0; cc < 2; ++cc) {
      int c = cc * 256 + tid;
      int r = c >> 2, kc = c & 3;
      gl2lds16(A + (bm + r) * (long)K + k0 + kc * 8, (char*)As + c * 16);
      gl2lds16(Bt + (bn + r) * (long)K + k0 + kc * 8, (char*)Bs + c * 16);
    }
    __syncthreads();
    bf16x8 af[4], bfr[4];
#pragma unroll
    for (int i = 0; i < 4; ++i)
      af[i] = *(const bf16x8*)(As + (wm + i * 16 + l15) * 32 + q4 * 8);
#pragma unroll
    for (int j = 0; j < 4; ++j)
      bfr[j] = *(const bf16x8*)(Bs + (wn + j * 16 + l15) * 32 + q4 * 8);
#pragma unroll
    for (int i = 0; i < 4; ++i)
#pragma unroll
      for (int j = 0; j < 4; ++j)
        acc[i][j] = __builtin_amdgcn_mfma_f32_16x16x32_bf16(af[i], bfr[j], acc[i][j], 0, 0, 0);
    __syncthreads();
  }

  const bool vrole = (role == 1) && (bn >= 512);
#pragma unroll
  for (int i = 0; i < 4; ++i) {
#pragma unroll
    for (int j = 0; j < 4; ++j) {
      long col = bn + wn + j * 16 + l15;
      if (vrole) {
        long h = (col - 512) >> 6, d = col & 63;
        long row0 = bm + wm + i * 16 + q4 * 4;
        long b = row0 >> 10, m0 = row0 & 1023;
        unsigned long long pk = (unsigned long long)bfbits(acc[i][j][0])
                              | ((unsigned long long)bfbits(acc[i][j][1]) << 16)
                              | ((unsigned long long)bfbits(acc[i][j][2]) << 32)
                              | ((unsigned long long)bfbits(acc[i][j][3]) << 48);
        *(unsigned long long*)(Vt + ((b * 8 + h) * 64 + d) * 1024 + m0) = pk;
      } else {
        long h = col >> 6, d = col & 63;
#pragma unroll
        for (int r = 0; r < 4; ++r) {
          long row = bm + wm + i * 16 + q4 * 4 + r;
          long b = row >> 10, n = row & 1023;
          float v = acc[i][j][r];
          if (role == 0) Qb[((b * 8 + h) * 1024 + n) * 64 + d] = bfbits(v * QSCALE);
          else           Kb[((b * 8 + h) * 1024 + n) * 64 + d] = bfbits(v);
        }
      }
    }
  }
}

// ---------------- flash attention: 128 q/block, 32 q/wave, S^T softmax ----------------
// grid (64 bh, 8 nb), 256 threads. KV tiles of 64, double-buffered. LDS 48KB.
// All LDS swizzle offsets are tile-invariant -> precomputed; t-loop unrolled x2 so
// the buffer index is compile-time (LDS bases fold to immediates).
__global__ __launch_bounds__(256)
void attn_kernel(const unsigned short* __restrict__ Qb,  // [64][1024][64] (pre-scaled)
                 const unsigned short* __restrict__ Kb,  // [64][1024][64]
                 const unsigned short* __restrict__ Vt,  // [64][64][1024]
                 unsigned short* __restrict__ Ob)        // [8192][512]
{
  __shared__ unsigned short Ksm[2][4096];  // [64 kv][64 d], 16B-chunk XOR swizzle
  __shared__ unsigned short Vsm[2][4096];  // [64 d][64 m], 16B-chunk XOR swizzle
  __shared__ unsigned short Psm[128 * 64]; // [128 q][64 kv], wave-private 32-row bands

  const int tid = threadIdx.x;
  const int wave = tid >> 6;
  const int lane = tid & 63;
  const int l15 = lane & 15;
  const int q4 = lane >> 4;
  const int bh = blockIdx.x;
  const int nb = blockIdx.y;

  const long qrow0 = (long)bh * 1024 + nb * 128 + wave * 32;

  // Q B-frags: B[n=l15 (qrow)][k=q4*8+j (d)], two 16-row groups
  bf16x8 qf[2][2];
#pragma unroll
  for (int qn = 0; qn < 2; ++qn)
#pragma unroll
    for (int ks = 0; ks < 2; ++ks)
      qf[qn][ks] = *(const bf16x8*)(Qb + (qrow0 + qn * 16 + l15) * 64 + ks * 32 + q4 * 8);

  floatx4 acc[2][4];
#pragma unroll
  for (int i = 0; i < 2; ++i)
#pragma unroll
    for (int d = 0; d < 4; ++d) { acc[i][d][0]=0.f; acc[i][d][1]=0.f; acc[i][d][2]=0.f; acc[i][d][3]=0.f; }
  float suml[2] = {0.0f, 0.0f};

  const unsigned short* Kbase = Kb + (long)bh * 65536;
  const unsigned short* Vbase = Vt + (long)bh * 65536;
  int koff[2], voff[2], lds16[2];
#pragma unroll
  for (int cc = 0; cc < 2; ++cc) {
    int c = cc * 256 + tid;
    int jrow = c >> 3;
    int cact = (c & 7) ^ (jrow & 7);
    koff[cc] = jrow * 64 + cact * 8;
    voff[cc] = jrow * 1024 + cact * 8;
    lds16[cc] = c * 16;
  }

  // tile-invariant LDS element offsets
  const int s7 = l15 & 7;
  int kfo[2][4];   // K/V fragment reads: [(x*16+l15)*64 + (((ks*4+q4)^s7)*8)]
  int pao[2][2];   // P A-frag reads
  int pwo[2][4];   // P writes
#pragma unroll
  for (int ks = 0; ks < 2; ++ks) {
#pragma unroll
    for (int jn = 0; jn < 4; ++jn)
      kfo[ks][jn] = (jn * 16 + l15) * 64 + (((ks * 4 + q4) ^ s7) * 8);
#pragma unroll
    for (int i = 0; i < 2; ++i)
      pao[ks][i] = (wave * 32 + i * 16 + l15) * 64 + (((ks * 4 + q4) ^ s7) * 8);
  }
#pragma unroll
  for (int qn = 0; qn < 2; ++qn)
#pragma unroll
    for (int jn = 0; jn < 4; ++jn)
      pwo[qn][jn] = (wave * 32 + qn * 16 + l15) * 64 + (((jn * 2 + (q4 >> 1)) ^ s7) * 8) + (q4 & 1) * 4;

#pragma unroll
  for (int cc = 0; cc < 2; ++cc) {
    gl2lds16(Kbase + koff[cc], (char*)Ksm[0] + lds16[cc]);
    gl2lds16(Vbase + voff[cc], (char*)Vsm[0] + lds16[cc]);
  }

#define ATTN_TILE(TIDX, CUR, STAGE)                                                          \
  {                                                                                          \
    __syncthreads();                                                                         \
    if (STAGE) {                                                                             \
      _Pragma("unroll")                                                                      \
      for (int cc = 0; cc < 2; ++cc) {                                                       \
        gl2lds16(Kbase + ((TIDX) + 1) * 4096 + koff[cc], (char*)Ksm[(CUR) ^ 1] + lds16[cc]); \
        gl2lds16(Vbase + ((TIDX) + 1) * 64 + voff[cc], (char*)Vsm[(CUR) ^ 1] + lds16[cc]);   \
      }                                                                                      \
    }                                                                                        \
    floatx4 st[4][2];                                                                        \
    _Pragma("unroll")                                                                        \
    for (int jn = 0; jn < 4; ++jn)                                                           \
      _Pragma("unroll")                                                                      \
      for (int qn = 0; qn < 2; ++qn) {                                                       \
        st[jn][qn][0] = 0.f; st[jn][qn][1] = 0.f; st[jn][qn][2] = 0.f; st[jn][qn][3] = 0.f;  \
      }                                                                                      \
    _Pragma("unroll")                                                                        \
    for (int ks = 0; ks < 2; ++ks) {                                                         \
      bf16x8 kfr[4];                                                                         \
      _Pragma("unroll")                                                                      \
      for (int jn = 0; jn < 4; ++jn)                                                         \
        kfr[jn] = *(const bf16x8*)(Ksm[(CUR)] + kfo[ks][jn]);                                \
      _Pragma("unroll")                                                                      \
      for (int jn = 0; jn < 4; ++jn)                                                         \
        _Pragma("unroll")                                                                    \
        for (int qn = 0; qn < 2; ++qn)                                                       \
          st[jn][qn] = __builtin_amdgcn_mfma_f32_16x16x32_bf16(kfr[jn], qf[qn][ks],          \
                                                               st[jn][qn], 0, 0, 0);         \
    }                                                                                        \
    _Pragma("unroll")                                                                        \
    for (int qn = 0; qn < 2; ++qn) {                                                         \
      _Pragma("unroll")                                                                      \
      for (int jn = 0; jn < 4; ++jn) {                                                       \
        float p0 = fast_exp2(st[jn][qn][0]);                                                 \
        float p1 = fast_exp2(st[jn][qn][1]);                                                 \
        float p2 = fast_exp2(st[jn][qn][2]);                                                 \
        float p3 = fast_exp2(st[jn][qn][3]);                                                 \
        suml[qn] += (p0 + p1) + (p2 + p3);                                                   \
        unsigned int lo = (unsigned int)bfbits(p0) | ((unsigned int)bfbits(p1) << 16);       \
        unsigned int hi = (unsigned int)bfbits(p2) | ((unsigned int)bfbits(p3) << 16);       \
        unsigned long long pk = (unsigned long long)lo | ((unsigned long long)hi << 32);     \
        *(unsigned long long*)(Psm + pwo[qn][jn]) = pk;                                      \
      }                                                                                      \
    }                                                                                        \
    __asm__ volatile("s_waitcnt lgkmcnt(0)" ::: "memory");                                   \
    _Pragma("unroll")                                                                        \
    for (int ks = 0; ks < 2; ++ks) {                                                         \
      bf16x8 pa[2], vb[4];                                                                   \
      _Pragma("unroll")                                                                      \
      for (int i = 0; i < 2; ++i)                                                            \
        pa[i] = *(const bf16x8*)(Psm + pao[ks][i]);                                          \
      _Pragma("unroll")                                                                      \
      for (int dn = 0; dn < 4; ++dn)                                                         \
        vb[dn] = *(const bf16x8*)(Vsm[(CUR)] + kfo[ks][dn]);                                 \
      _Pragma("unroll")                                                                      \
      for (int i = 0; i < 2; ++i)                                                            \
        _Pragma("unroll")                                                                    \
        for (int dn = 0; dn < 4; ++dn)                                                       \
          acc[i][dn] = __builtin_amdgcn_mfma_f32_16x16x32_bf16(pa[i], vb[dn],                \
                                                               acc[i][dn], 0, 0, 0);         \
    }                                                                                        \
  }

  for (int tt = 0; tt < 8; ++tt) {
    ATTN_TILE(2 * tt, 0, true);
    ATTN_TILE(2 * tt + 1, 1, (tt < 7));
  }
#undef ATTN_TILE

  // row sums: lanes l15, l15+16, l15+32, l15+48 hold partials for q=qn*16+l15
  float inv[2], invr[2][4];
#pragma unroll
  for (int qn = 0; qn < 2; ++qn) {
    float l = suml[qn];
    l += __shfl_xor(l, 16, 64);
    l += __shfl_xor(l, 32, 64);
    inv[qn] = 1.0f / l;
#pragma unroll
    for (int r = 0; r < 4; ++r) invr[qn][r] = __shfl(inv[qn], q4 * 4 + r, 64);
  }

  const int b = bh >> 3, h = bh & 7;
#pragma unroll
  for (int i = 0; i < 2; ++i) {
#pragma unroll
    for (int dn = 0; dn < 4; ++dn) {
#pragma unroll
      for (int r = 0; r < 4; ++r) {
        long row = (long)b * 1024 + nb * 128 + wave * 32 + i * 16 + q4 * 4 + r;
        long col = h * 64 + dn * 16 + l15;
        Ob[row * 512 + col] = bfbits(acc[i][dn][r] * invr[i][r]);
      }
    }
  }
}

// ---------------- final GEMM: out = Ob * WoT^T + bias, fp32 out, 64x128x32 ----------------
__global__ __launch_bounds__(256)
void out_gemm(const unsigned short* __restrict__ A,   // Ob [8192][512]
              const unsigned short* __restrict__ Bt,  // WoT [512][512]
              float* __restrict__ outF, const float* __restrict__ bias) {
  __shared__ unsigned short As[64 * 32];
  __shared__ unsigned short Bs[128 * 32];

  const int tid = threadIdx.x;
  const int wave = tid >> 6;
  const int lane = tid & 63;
  const int l15 = lane & 15;
  const int q4 = lane >> 4;
  const int wm = (wave & 1) * 32;
  const int wn = (wave >> 1) * 64;
  const long bm = (long)blockIdx.y * 64;
  const long bn = (long)blockIdx.x * 128;
  const int K = 512, N = 512;

  floatx4 acc[2][4];
#pragma unroll
  for (int i = 0; i < 2; ++i)
#pragma unroll
    for (int j = 0; j < 4; ++j) { acc[i][j][0]=0.f; acc[i][j][1]=0.f; acc[i][j][2]=0.f; acc[i][j][3]=0.f; }

  for (int k0 = 0; k0 < K; k0 += 32) {
    {
      int r = tid >> 2, kc = tid & 3;
      gl2lds16(A + (bm + r) * (long)K + k0 + kc * 8, (char*)As + tid * 16);
    }
#pragma unroll
    for (int cc = 0; cc < 2; ++cc) {
      int c = cc * 256 + tid;
      int r = c >> 2, kc = c & 3;
      gl2lds16(Bt + (bn + r) * (long)K + k0 + kc * 8, (char*)Bs + c * 16);
    }
    __syncthreads();
    bf16x8 af[2], bfr[4];
#pragma unroll
    for (int i = 0; i < 2; ++i)
      af[i] = *(const bf16x8*)(As + (wm + i * 16 + l15) * 32 + q4 * 8);
#pragma unroll
    for (int j = 0; j < 4; ++j)
      bfr[j] = *(const bf16x8*)(Bs + (wn + j * 16 + l15) * 32 + q4 * 8);
#pragma unroll
    for (int i = 0; i < 2; ++i)
#pragma unroll
      for (int j = 0; j < 4; ++j)
        acc[i][j] = __builtin_amdgcn_mfma_f32_16x16x32_bf16(af[i], bfr[j], acc[i][j], 0, 0, 0);
    __syncthreads();
  }

#pragma unroll
  for (int i = 0; i < 2; ++i) {
#pragma unroll
    for (int j = 0; j < 4; ++j) {
      long col = bn + wn + j * 16 + l15;
      float bv = bias[col];
#pragma unroll
      for (int r = 0; r < 4; ++r) {
        long row = bm + wm + i * 16 + q4 * 4 + r;
        outF[row * (long)N + col] = acc[i][j][r] + bv;
      }
    }
  }
}

extern "C" void kernel_launch(void* const* d_in, const int* in_sizes, int n_in,
                              void* d_out, int out_size, void* d_ws, size_t ws_size,
                              hipStream_t stream) {
  const float* x   = (const float*)d_in[0];   // [8,1024,512]
  const float* ctx = (const float*)d_in[1];   // [8,1024,512]
  const float* Wq  = (const float*)d_in[2];   // [512,512]
  const float* Wkv = (const float*)d_in[3];   // [512,1024]
  const float* Wo  = (const float*)d_in[4];   // [512,512]
  const float* bo  = (const float*)d_in[5];   // [512]
  float* out = (float*)d_out;

  char* ws = (char*)d_ws;
  unsigned short* Xb   = (unsigned short*)(ws);                 // 8 MB
  unsigned short* Cb   = (unsigned short*)(ws + (8u  << 20));   // 8 MB
  unsigned short* WqT  = (unsigned short*)(ws + (16u << 20));   // 0.5 MB
  unsigned short* WkvT = (unsigned short*)(ws + (17u << 20));   // 1 MB
  unsigned short* WoT  = (unsigned short*)(ws + (19u << 20));   // 0.5 MB
  unsigned short* Qb   = (unsigned short*)(ws + (20u << 20));   // 8 MB
  unsigned short* Kb   = (unsigned short*)(ws + (28u << 20));   // 8 MB
  unsigned short* Vt   = (unsigned short*)(ws + (36u << 20));   // 8 MB
  unsigned short* Ob   = (unsigned short*)(ws + (44u << 20));   // 8 MB  (total 52 MB)

  prep_kernel<<<9216, 256, 0, stream>>>(x, ctx, Wq, Wkv, Wo, Xb, Cb, WqT, WkvT, WoT);
  proj_gemm<<<768, 256, 0, stream>>>(Xb, Cb, WqT, WkvT, Qb, Kb, Vt);
  attn_kernel<<<dim3(64, 8), 256, 0, stream>>>(Qb, Kb, Vt, Ob);
  out_gemm<<<dim3(4, 128), 256, 0, stream>>>(Ob, WoT, out, bo);
}